// Round 5
// baseline (865.842 us; speedup 1.0000x reference)
//
#include <hip/hip_runtime.h>
#include <math.h>

#define D_MODEL 768
#define NUM_HEADS 12
#define D_K 64
#define SEQ 4096
#define BATCH 2
#define BH_ (BATCH*NUM_HEADS)
#define MROWS (BATCH*SEQ)     // 8192

typedef __attribute__((ext_vector_type(8))) short bf16x8;
typedef __attribute__((ext_vector_type(4))) float f32x4;
typedef unsigned short u16;
typedef unsigned int u32;

__device__ __forceinline__ u16 f2bf(float f) {
    union { float f; u32 u; } v; v.f = f;
    u32 r = v.u + 0x7fffu + ((v.u >> 16) & 1u);   // RNE
    return (u16)(r >> 16);
}
__device__ __forceinline__ float bf2f(u16 h) {
    union { u32 u; float f; } v; v.u = (u32)h << 16; return v.f;
}
__device__ __forceinline__ void split_bf(float v, u16& h, u16& l) {
    h = f2bf(v); l = f2bf(v - bf2f(h));
}
__device__ __forceinline__ float fast_exp2(float x) {
#if __has_builtin(__builtin_amdgcn_exp2f)
    return __builtin_amdgcn_exp2f(x);
#else
    return exp2f(x);
#endif
}
// async global->LDS DMA: LDS dest = uniform base + lane*16
__device__ __forceinline__ void gload_lds16(const u16* g, u16* l) {
    __builtin_amdgcn_global_load_lds(
        (const __attribute__((address_space(1))) void*)g,
        (__attribute__((address_space(3))) void*)l, 16, 0, 0);
}

// ---------------------------------------------------------------------------
// convert x -> Xh, Xl (split bf16).  8 elements / thread.
// ---------------------------------------------------------------------------
__global__ __launch_bounds__(256)
void convert_x(const float* __restrict__ x, u16* __restrict__ Xh, u16* __restrict__ Xl)
{
    int i = (blockIdx.x * 256 + threadIdx.x) * 8;
    float4 a = *(const float4*)&x[i];
    float4 b = *(const float4*)&x[i + 4];
    float vs[8] = {a.x, a.y, a.z, a.w, b.x, b.y, b.z, b.w};
    u16 hs[8], ls[8];
#pragma unroll
    for (int j = 0; j < 8; ++j) split_bf(vs[j], hs[j], ls[j]);
    uint4 H, L;
    H.x = (u32)hs[0] | ((u32)hs[1] << 16); H.y = (u32)hs[2] | ((u32)hs[3] << 16);
    H.z = (u32)hs[4] | ((u32)hs[5] << 16); H.w = (u32)hs[6] | ((u32)hs[7] << 16);
    L.x = (u32)ls[0] | ((u32)ls[1] << 16); L.y = (u32)ls[2] | ((u32)ls[3] << 16);
    L.z = (u32)ls[4] | ((u32)ls[5] << 16); L.w = (u32)ls[6] | ((u32)ls[7] << 16);
    *(uint4*)&Xh[i] = H;
    *(uint4*)&Xl[i] = L;
}

// ---------------------------------------------------------------------------
// convert weights.  z=0: Wq->h+l  z=1: Wk->h+l  z=2: Wv->h  z=3: Wo->h
// ---------------------------------------------------------------------------
__global__ __launch_bounds__(256)
void convert_w(const float* __restrict__ Wq, const float* __restrict__ Wk,
               const float* __restrict__ Wv, const float* __restrict__ Wo,
               u16* __restrict__ Wqh, u16* __restrict__ Wql,
               u16* __restrict__ Wkh, u16* __restrict__ Wkl,
               u16* __restrict__ Wvh, u16* __restrict__ Woh)
{
    const int z = blockIdx.y;
    const float* __restrict__ src = (z==0)?Wq:(z==1)?Wk:(z==2)?Wv:Wo;
    u16* __restrict__ dh = (z==0)?Wqh:(z==1)?Wkh:(z==2)?Wvh:Woh;
    u16* __restrict__ dl = (z==0)?Wql:(z==1)?Wkl:nullptr;

    int i = (blockIdx.x * 256 + threadIdx.x) * 8;
    float4 a = *(const float4*)&src[i];
    float4 b = *(const float4*)&src[i + 4];
    float vs[8] = {a.x, a.y, a.z, a.w, b.x, b.y, b.z, b.w};
    u16 hs[8], ls[8];
#pragma unroll
    for (int j = 0; j < 8; ++j) split_bf(vs[j], hs[j], ls[j]);
    uint4 H;
    H.x = (u32)hs[0] | ((u32)hs[1] << 16); H.y = (u32)hs[2] | ((u32)hs[3] << 16);
    H.z = (u32)hs[4] | ((u32)hs[5] << 16); H.w = (u32)hs[6] | ((u32)hs[7] << 16);
    *(uint4*)&dh[i] = H;
    if (dl) {
        uint4 L;
        L.x = (u32)ls[0] | ((u32)ls[1] << 16); L.y = (u32)ls[2] | ((u32)ls[3] << 16);
        L.z = (u32)ls[4] | ((u32)ls[5] << 16); L.w = (u32)ls[6] | ((u32)ls[7] << 16);
        *(uint4*)&dl[i] = L;
    }
}

// ---------------------------------------------------------------------------
// QKV projection, MFMA.  128x128 tile, BK=32, 4 waves (2x2 of 64x64).
// Staging via global_load_lds (m97 pattern, unpadded 32-elem rows).
// z=0/1 (Q/K): split-bf16 (3 mfma), split-bf16 output [bh][l][dk].
//   Q scale = (1/8)*log2(e): attention uses exp2, so P = 2^(s*log2 e) = e^s.
// z=2   (V)  : plain bf16 (1 mfma), bf16 output transposed+permuted [bh][dk][l'].
// ---------------------------------------------------------------------------
__global__ __launch_bounds__(256)
void proj_gemm(const u16* __restrict__ Xh, const u16* __restrict__ Xl,
               const u16* __restrict__ Wqh, const u16* __restrict__ Wql,
               const u16* __restrict__ Wkh, const u16* __restrict__ Wkl,
               const u16* __restrict__ Wvh,
               const float* __restrict__ bq, const float* __restrict__ bk,
               const float* __restrict__ bv,
               u16* __restrict__ Qh, u16* __restrict__ Ql,
               u16* __restrict__ Kh, u16* __restrict__ Kl,
               u16* __restrict__ Vh)
{
    const int z = blockIdx.z;
    const u16* __restrict__ Bh_ = (z==0)?Wqh:(z==1)?Wkh:Wvh;
    const u16* __restrict__ Bl_ = (z==0)?Wql:Wkl;   // unused when z==2
    const float* __restrict__ bias = (z==0)?bq:(z==1)?bk:bv;
    const bool spl = (z < 2);

    __shared__ __align__(16) u16 sAh[128*32];
    __shared__ __align__(16) u16 sAl[128*32];
    __shared__ __align__(16) u16 sBh[128*32];
    __shared__ __align__(16) u16 sBl[128*32];

    const int tid  = threadIdx.x;
    const int lane = tid & 63;
    const int ln   = lane & 15, quad = lane >> 4;
    const int w    = tid >> 6;
    const int wr   = (w & 1) * 64;
    const int wc   = (w >> 1) * 64;
    const int m0   = blockIdx.x * 128;
    const int n0   = blockIdx.y * 128;

    const int lr = lane >> 2;          // 0..15 row within 16-row chunk
    const int lc = (lane & 3) * 8;     // u16 col (0,8,16,24)

    f32x4 acc[4][4];
    const f32x4 z4 = {0.f,0.f,0.f,0.f};
#pragma unroll
    for (int s = 0; s < 4; ++s)
#pragma unroll
        for (int j = 0; j < 4; ++j) acc[s][j] = z4;

#pragma unroll 1
    for (int k0 = 0; k0 < D_MODEL; k0 += 32) {
        __syncthreads();   // previous tile fully consumed before DMA overwrite
#pragma unroll
        for (int cc = 0; cc < 2; ++cc) {
            const int c  = w*2 + cc;        // chunk 0..7 (16 rows each)
            const int gr = c*16 + lr;
            gload_lds16(&Xh [(size_t)(m0 + gr)*D_MODEL + k0 + lc], &sAh[c*512]);
            gload_lds16(&Bh_[(size_t)(n0 + gr)*D_MODEL + k0 + lc], &sBh[c*512]);
            if (spl) {
                gload_lds16(&Xl [(size_t)(m0 + gr)*D_MODEL + k0 + lc], &sAl[c*512]);
                gload_lds16(&Bl_[(size_t)(n0 + gr)*D_MODEL + k0 + lc], &sBl[c*512]);
            }
        }
        __syncthreads();   // drains vmcnt -> DMA data visible

        bf16x8 a_h[4], a_l[4];
#pragma unroll
        for (int s = 0; s < 4; ++s) {
            a_h[s] = *(const bf16x8*)&sAh[(wr + s*16 + ln)*32 + quad*8];
            if (spl) a_l[s] = *(const bf16x8*)&sAl[(wr + s*16 + ln)*32 + quad*8];
        }
#pragma unroll
        for (int j0 = 0; j0 < 4; ++j0) {
            bf16x8 b_h = *(const bf16x8*)&sBh[(wc + j0*16 + ln)*32 + quad*8];
            bf16x8 b_l;
            if (spl) b_l = *(const bf16x8*)&sBl[(wc + j0*16 + ln)*32 + quad*8];
#pragma unroll
            for (int s = 0; s < 4; ++s) {
                f32x4 t = __builtin_amdgcn_mfma_f32_16x16x32_bf16(a_h[s], b_h, acc[s][j0], 0, 0, 0);
                if (spl) {
                    t = __builtin_amdgcn_mfma_f32_16x16x32_bf16(a_l[s], b_h, t, 0, 0, 0);
                    t = __builtin_amdgcn_mfma_f32_16x16x32_bf16(a_h[s], b_l, t, 0, 0, 0);
                }
                acc[s][j0] = t;
            }
        }
    }

    // Q carries 1/8 * log2(e) so attn can use exp2 directly.
    const float scale = (z == 0) ? 0.125f * 1.4426950408889634f : 1.0f;
#pragma unroll
    for (int s = 0; s < 4; ++s) {
#pragma unroll
        for (int j0 = 0; j0 < 4; ++j0) {
            const int dfull = n0 + wc + j0*16 + ln;
            const int hh = dfull >> 6, dd = dfull & 63;
            const float bia = bias[dfull];
#pragma unroll
            for (int i = 0; i < 4; ++i) {
                int m  = m0 + wr + s*16 + quad*4 + i;
                int b_ = m >> 12, l = m & (SEQ-1);
                float v = (acc[s][j0][i] + bia) * scale;
                if (z < 2) {
                    u16 vh, vl; split_bf(v, vh, vl);
                    size_t idx = ((size_t)(b_*NUM_HEADS + hh)*SEQ + l)*D_K + dd;
                    if (z == 0) { Qh[idx] = vh; Ql[idx] = vl; }
                    else        { Kh[idx] = vh; Kl[idx] = vl; }
                } else {
                    int lp = (l & ~63) | ((l & 15) << 2) | ((l >> 4) & 3);
                    Vh[((size_t)(b_*NUM_HEADS + hh)*D_K + dd)*SEQ + lp] = f2bf(v);
                }
            }
        }
    }
}

// ---------------------------------------------------------------------------
// Output projection, MFMA plain bf16, global_load_lds staging.
// ---------------------------------------------------------------------------
__global__ __launch_bounds__(256)
void out_gemm(const u16* __restrict__ Ah, const u16* __restrict__ Bh_,
              const float* __restrict__ bias, float* __restrict__ C)
{
    __shared__ __align__(16) u16 sAh[128*32];
    __shared__ __align__(16) u16 sBh[128*32];

    const int tid  = threadIdx.x;
    const int lane = tid & 63;
    const int ln   = lane & 15, quad = lane >> 4;
    const int w    = tid >> 6;
    const int wr   = (w & 1) * 64;
    const int wc   = (w >> 1) * 64;
    const int m0   = blockIdx.x * 128;
    const int n0   = blockIdx.y * 128;
    const int lr = lane >> 2;
    const int lc = (lane & 3) * 8;

    f32x4 acc[4][4];
    const f32x4 z4 = {0.f,0.f,0.f,0.f};
#pragma unroll
    for (int s = 0; s < 4; ++s)
#pragma unroll
        for (int j = 0; j < 4; ++j) acc[s][j] = z4;

#pragma unroll 1
    for (int k0 = 0; k0 < D_MODEL; k0 += 32) {
        __syncthreads();
#pragma unroll
        for (int cc = 0; cc < 2; ++cc) {
            const int c  = w*2 + cc;
            const int gr = c*16 + lr;
            gload_lds16(&Ah [(size_t)(m0 + gr)*D_MODEL + k0 + lc], &sAh[c*512]);
            gload_lds16(&Bh_[(size_t)(n0 + gr)*D_MODEL + k0 + lc], &sBh[c*512]);
        }
        __syncthreads();

        bf16x8 a_h[4];
#pragma unroll
        for (int s = 0; s < 4; ++s)
            a_h[s] = *(const bf16x8*)&sAh[(wr + s*16 + ln)*32 + quad*8];
#pragma unroll
        for (int j0 = 0; j0 < 4; ++j0) {
            bf16x8 b_h = *(const bf16x8*)&sBh[(wc + j0*16 + ln)*32 + quad*8];
#pragma unroll
            for (int s = 0; s < 4; ++s)
                acc[s][j0] = __builtin_amdgcn_mfma_f32_16x16x32_bf16(a_h[s], b_h, acc[s][j0], 0, 0, 0);
        }
    }

#pragma unroll
    for (int s = 0; s < 4; ++s) {
#pragma unroll
        for (int j0 = 0; j0 < 4; ++j0) {
            const int dfull = n0 + wc + j0*16 + ln;
            const float bia = bias[dfull];
#pragma unroll
            for (int i = 0; i < 4; ++i) {
                int m = m0 + wr + s*16 + quad*4 + i;
                C[(size_t)m*D_MODEL + dfull] = acc[s][j0][i] + bia;
            }
        }
    }
}

// ---------------------------------------------------------------------------
// MFMA flash attention — barrier-free, staging-free.
// K and V fragments are loaded global->VGPR directly (B-operand lane layout
// is contiguous-8 in memory: K natural [key][dk], V transposed+permuted
// [bh][dk][key']). Only P round-trips through LDS (wave-private region, no
// __syncthreads anywhere). No-max softmax via exp2 (Q carries log2e/8);
// l accumulated by ones-MFMA over the same truncated P used for PV.
// LDS = 18.4 KB; launch_bounds(256,4) caps VGPR at 128 -> ~16 waves/CU.
// ---------------------------------------------------------------------------
#define LPP 72

__global__ __launch_bounds__(256, 4)
void attn_mfma(const u16* __restrict__ Qh, const u16* __restrict__ Ql,
               const u16* __restrict__ Kh, const u16* __restrict__ Kl,
               const u16* __restrict__ Vh, u16* __restrict__ Obh)
{
    __shared__ __align__(16) u16 sP[128*LPP];

    const int tid  = threadIdx.x;
    const int w    = tid >> 6;
    const int lane = tid & 63;
    const int ln   = lane & 15;
    const int quad = lane >> 4;
    const int bh   = blockIdx.y;
    const int b_   = bh / NUM_HEADS;
    const int h    = bh % NUM_HEADS;
    const int q0   = blockIdx.x * 128;
    const int wq   = w * 32;

    const size_t bhL = (size_t)bh * SEQ;
    const u16* __restrict__ Kbh = Kh + bhL * D_K;                 // [key][dk]
    const u16* __restrict__ Kbl = Kl + bhL * D_K;
    const u16* __restrict__ Vb  = Vh + (size_t)bh * D_K * SEQ;    // [dk][key']

    // Q fragments (A-layout), hi & lo
    bf16x8 qh[2][2], ql[2][2];
#pragma unroll
    for (int s = 0; s < 2; ++s) {
        const size_t row = bhL + q0 + wq + s*16 + ln;
        const u16* qph = Qh + row * D_K;
        const u16* qpl = Ql + row * D_K;
        qh[s][0] = *(const bf16x8*)&qph[quad*8];
        qh[s][1] = *(const bf16x8*)&qph[32 + quad*8];
        ql[s][0] = *(const bf16x8*)&qpl[quad*8];
        ql[s][1] = *(const bf16x8*)&qpl[32 + quad*8];
    }

    const bf16x8 ones = {(short)0x3F80,(short)0x3F80,(short)0x3F80,(short)0x3F80,
                         (short)0x3F80,(short)0x3F80,(short)0x3F80,(short)0x3F80};
    const f32x4 z4 = {0.f,0.f,0.f,0.f};
    f32x4 lacc[2] = {z4, z4};
    f32x4 o[2][4];
#pragma unroll
    for (int s = 0; s < 2; ++s)
#pragma unroll
        for (int d0 = 0; d0 < 4; ++d0) o[s][d0] = z4;

#pragma unroll 1
    for (int kt = 0; kt < SEQ; kt += 64) {
        // ---- S = Q K^T : K B-frags straight from global ----
        f32x4 S[2][4];
#pragma unroll
        for (int j0 = 0; j0 < 4; ++j0) {
            const u16* krh = &Kbh[(size_t)(kt + j0*16 + ln)*D_K + quad*8];
            const u16* krl = &Kbl[(size_t)(kt + j0*16 + ln)*D_K + quad*8];
            bf16x8 kh0 = *(const bf16x8*)krh;
            bf16x8 kh1 = *(const bf16x8*)(krh + 32);
            bf16x8 kl0 = *(const bf16x8*)krl;
            bf16x8 kl1 = *(const bf16x8*)(krl + 32);
#pragma unroll
            for (int s = 0; s < 2; ++s) {
                f32x4 a = z4;
                a = __builtin_amdgcn_mfma_f32_16x16x32_bf16(qh[s][0], kh0, a, 0, 0, 0);
                a = __builtin_amdgcn_mfma_f32_16x16x32_bf16(ql[s][0], kh0, a, 0, 0, 0);
                a = __builtin_amdgcn_mfma_f32_16x16x32_bf16(qh[s][0], kl0, a, 0, 0, 0);
                a = __builtin_amdgcn_mfma_f32_16x16x32_bf16(qh[s][1], kh1, a, 0, 0, 0);
                a = __builtin_amdgcn_mfma_f32_16x16x32_bf16(ql[s][1], kh1, a, 0, 0, 0);
                a = __builtin_amdgcn_mfma_f32_16x16x32_bf16(qh[s][1], kl1, a, 0, 0, 0);
                S[s][j0] = a;
            }
        }

        // ---- V B-frags straight from global (latency hidden by softmax) ----
        bf16x8 vf[4][2];
#pragma unroll
        for (int d0 = 0; d0 < 4; ++d0) {
            const u16* vr = &Vb[(size_t)(d0*16 + ln)*SEQ + kt + quad*8];
            vf[d0][0] = *(const bf16x8*)vr;
            vf[d0][1] = *(const bf16x8*)(vr + 32);
        }

        // ---- P = exp2(S) (Q carries log2e); trunc-pack via v_perm ----
#pragma unroll
        for (int s = 0; s < 2; ++s) {
#pragma unroll
            for (int i = 0; i < 4; ++i) {
                u32 u0 = __float_as_uint(fast_exp2(S[s][0][i]));
                u32 u1 = __float_as_uint(fast_exp2(S[s][1][i]));
                u32 u2 = __float_as_uint(fast_exp2(S[s][2][i]));
                u32 u3 = __float_as_uint(fast_exp2(S[s][3][i]));
                uint2 pk;
                pk.x = __builtin_amdgcn_perm(u1, u0, 0x07060302u);  // {u0.hi, u1.hi}
                pk.y = __builtin_amdgcn_perm(u3, u2, 0x07060302u);  // {u2.hi, u3.hi}
                int prow = wq + s*16 + quad*4 + i;
                *(uint2*)&sP[prow*LPP + ln*4] = pk;
            }
        }

        // ---- O += P V ; l += P @ ones  (sP wave-private: no barrier) ----
        bf16x8 pa[2][2];
#pragma unroll
        for (int s = 0; s < 2; ++s) {
            const u16* pp = &sP[(wq + s*16 + ln)*LPP];
            pa[s][0] = *(const bf16x8*)&pp[quad*8];
            pa[s][1] = *(const bf16x8*)&pp[32 + quad*8];
        }
#pragma unroll
        for (int s = 0; s < 2; ++s) {
            lacc[s] = __builtin_amdgcn_mfma_f32_16x16x32_bf16(pa[s][0], ones, lacc[s], 0, 0, 0);
            lacc[s] = __builtin_amdgcn_mfma_f32_16x16x32_bf16(pa[s][1], ones, lacc[s], 0, 0, 0);
        }
#pragma unroll
        for (int d0 = 0; d0 < 4; ++d0) {
#pragma unroll
            for (int s = 0; s < 2; ++s) {
                f32x4 a = o[s][d0];
                a = __builtin_amdgcn_mfma_f32_16x16x32_bf16(pa[s][0], vf[d0][0], a, 0, 0, 0);
                a = __builtin_amdgcn_mfma_f32_16x16x32_bf16(pa[s][1], vf[d0][1], a, 0, 0, 0);
                o[s][d0] = a;
            }
        }
    }

    // ---- epilogue: l row-sums already in lacc (all lanes); store bf16 ----
#pragma unroll
    for (int s = 0; s < 2; ++s) {
        float inv[4];
#pragma unroll
        for (int i = 0; i < 4; ++i) inv[i] = 1.0f / lacc[s][i];
#pragma unroll
        for (int d0 = 0; d0 < 4; ++d0) {
#pragma unroll
            for (int i = 0; i < 4; ++i) {
                int q = q0 + wq + s*16 + quad*4 + i;
                Obh[((size_t)b_*SEQ + q)*D_MODEL + h*D_K + d0*16 + ln] =
                    f2bf(o[s][d0][i] * inv[i]);
            }
        }
    }
}

extern "C" void kernel_launch(void* const* d_in, const int* in_sizes, int n_in,
                              void* d_out, int out_size, void* d_ws, size_t ws_size,
                              hipStream_t stream)
{
    const float* x  = (const float*)d_in[0];
    const float* Wq = (const float*)d_in[1];
    const float* bq = (const float*)d_in[2];
    const float* Wk = (const float*)d_in[3];
    const float* bk = (const float*)d_in[4];
    const float* Wv = (const float*)d_in[5];
    const float* bv = (const float*)d_in[6];
    const float* Wo = (const float*)d_in[7];
    const float* bo = (const float*)d_in[8];
    float* out = (float*)d_out;

    const size_t nX = (size_t)MROWS * D_MODEL;    // 6291456
    const size_t nW = (size_t)D_MODEL * D_MODEL;  // 589824

    u16* Xh  = (u16*)d_ws;
    u16* Xl  = Xh  + nX;
    u16* Wqh = Xl  + nX;
    u16* Wql = Wqh + nW;
    u16* Wkh = Wql + nW;
    u16* Wkl = Wkh + nW;
    u16* Wvh = Wkl + nW;
    u16* Woh = Wvh + nW;
    u16* Qh  = Woh + nW;
    u16* Ql  = Qh  + nX;
    u16* Kh  = Ql  + nX;
    u16* Kl  = Kh  + nX;
    u16* Vh  = Kl  + nX;
    u16* Obh = Xh;                 // alias: Xh/Xl dead after proj_gemm

    dim3 blk(256);
    convert_x<<<dim3(nX/(256*8)), blk, 0, stream>>>(x, Xh, Xl);
    convert_w<<<dim3(nW/(256*8), 4), blk, 0, stream>>>(Wq, Wk, Wv, Wo,
                                                       Wqh, Wql, Wkh, Wkl, Wvh, Woh);
    proj_gemm<<<dim3(MROWS/128, D_MODEL/128, 3), blk, 0, stream>>>(
        Xh, Xl, Wqh, Wql, Wkh, Wkl, Wvh, bq, bk, bv, Qh, Ql, Kh, Kl, Vh);
    attn_mfma<<<dim3(SEQ/128, BH_), blk, 0, stream>>>(Qh, Ql, Kh, Kl, Vh, Obh);
    out_gemm<<<dim3(MROWS/128, D_MODEL/128), blk, 0, stream>>>(Obh, Woh, bo, out);
}

// Round 6
// 463.508 us; speedup vs baseline: 1.8680x; 1.8680x over previous
//
#include <hip/hip_runtime.h>
#include <math.h>

#define D_MODEL 768
#define NUM_HEADS 12
#define D_K 64
#define SEQ 4096
#define BATCH 2
#define BH_ (BATCH*NUM_HEADS)
#define MROWS (BATCH*SEQ)     // 8192

typedef __attribute__((ext_vector_type(8))) short bf16x8;
typedef __attribute__((ext_vector_type(4))) float f32x4;
typedef unsigned short u16;
typedef unsigned int u32;

__device__ __forceinline__ u16 f2bf(float f) {
    union { float f; u32 u; } v; v.f = f;
    u32 r = v.u + 0x7fffu + ((v.u >> 16) & 1u);   // RNE
    return (u16)(r >> 16);
}
__device__ __forceinline__ float bf2f(u16 h) {
    union { u32 u; float f; } v; v.u = (u32)h << 16; return v.f;
}
__device__ __forceinline__ void split_bf(float v, u16& h, u16& l) {
    h = f2bf(v); l = f2bf(v - bf2f(h));
}
__device__ __forceinline__ float fast_exp2(float x) {
#if __has_builtin(__builtin_amdgcn_exp2f)
    return __builtin_amdgcn_exp2f(x);
#else
    return exp2f(x);
#endif
}
// async global->LDS DMA: LDS dest = uniform base + lane*16
__device__ __forceinline__ void gload_lds16(const u16* g, u16* l) {
    __builtin_amdgcn_global_load_lds(
        (const __attribute__((address_space(1))) void*)g,
        (__attribute__((address_space(3))) void*)l, 16, 0, 0);
}

// ---------------------------------------------------------------------------
// convert x -> Xh, Xl (split bf16).  8 elements / thread.
// ---------------------------------------------------------------------------
__global__ __launch_bounds__(256)
void convert_x(const float* __restrict__ x, u16* __restrict__ Xh, u16* __restrict__ Xl)
{
    int i = (blockIdx.x * 256 + threadIdx.x) * 8;
    float4 a = *(const float4*)&x[i];
    float4 b = *(const float4*)&x[i + 4];
    float vs[8] = {a.x, a.y, a.z, a.w, b.x, b.y, b.z, b.w};
    u16 hs[8], ls[8];
#pragma unroll
    for (int j = 0; j < 8; ++j) split_bf(vs[j], hs[j], ls[j]);
    uint4 H, L;
    H.x = (u32)hs[0] | ((u32)hs[1] << 16); H.y = (u32)hs[2] | ((u32)hs[3] << 16);
    H.z = (u32)hs[4] | ((u32)hs[5] << 16); H.w = (u32)hs[6] | ((u32)hs[7] << 16);
    L.x = (u32)ls[0] | ((u32)ls[1] << 16); L.y = (u32)ls[2] | ((u32)ls[3] << 16);
    L.z = (u32)ls[4] | ((u32)ls[5] << 16); L.w = (u32)ls[6] | ((u32)ls[7] << 16);
    *(uint4*)&Xh[i] = H;
    *(uint4*)&Xl[i] = L;
}

// ---------------------------------------------------------------------------
// convert weights.  z=0: Wq->h+l  z=1: Wk->h+l  z=2: Wv->h  z=3: Wo->h
// ---------------------------------------------------------------------------
__global__ __launch_bounds__(256)
void convert_w(const float* __restrict__ Wq, const float* __restrict__ Wk,
               const float* __restrict__ Wv, const float* __restrict__ Wo,
               u16* __restrict__ Wqh, u16* __restrict__ Wql,
               u16* __restrict__ Wkh, u16* __restrict__ Wkl,
               u16* __restrict__ Wvh, u16* __restrict__ Woh)
{
    const int z = blockIdx.y;
    const float* __restrict__ src = (z==0)?Wq:(z==1)?Wk:(z==2)?Wv:Wo;
    u16* __restrict__ dh = (z==0)?Wqh:(z==1)?Wkh:(z==2)?Wvh:Woh;
    u16* __restrict__ dl = (z==0)?Wql:(z==1)?Wkl:nullptr;

    int i = (blockIdx.x * 256 + threadIdx.x) * 8;
    float4 a = *(const float4*)&src[i];
    float4 b = *(const float4*)&src[i + 4];
    float vs[8] = {a.x, a.y, a.z, a.w, b.x, b.y, b.z, b.w};
    u16 hs[8], ls[8];
#pragma unroll
    for (int j = 0; j < 8; ++j) split_bf(vs[j], hs[j], ls[j]);
    uint4 H;
    H.x = (u32)hs[0] | ((u32)hs[1] << 16); H.y = (u32)hs[2] | ((u32)hs[3] << 16);
    H.z = (u32)hs[4] | ((u32)hs[5] << 16); H.w = (u32)hs[6] | ((u32)hs[7] << 16);
    *(uint4*)&dh[i] = H;
    if (dl) {
        uint4 L;
        L.x = (u32)ls[0] | ((u32)ls[1] << 16); L.y = (u32)ls[2] | ((u32)ls[3] << 16);
        L.z = (u32)ls[4] | ((u32)ls[5] << 16); L.w = (u32)ls[6] | ((u32)ls[7] << 16);
        *(uint4*)&dl[i] = L;
    }
}

// ---------------------------------------------------------------------------
// QKV projection, MFMA.  128x128 tile, BK=32, 4 waves (2x2 of 64x64).
// Staging via global_load_lds (m97 pattern, unpadded 32-elem rows).
// z=0/1 (Q/K): split-bf16 (3 mfma), split-bf16 output [bh][l][dk].
//   Q scale = (1/8)*log2(e): attention uses exp2, so P = 2^(s*log2 e) = e^s.
// z=2   (V)  : plain bf16 (1 mfma), bf16 output transposed+permuted [bh][dk][l'].
// ---------------------------------------------------------------------------
__global__ __launch_bounds__(256)
void proj_gemm(const u16* __restrict__ Xh, const u16* __restrict__ Xl,
               const u16* __restrict__ Wqh, const u16* __restrict__ Wql,
               const u16* __restrict__ Wkh, const u16* __restrict__ Wkl,
               const u16* __restrict__ Wvh,
               const float* __restrict__ bq, const float* __restrict__ bk,
               const float* __restrict__ bv,
               u16* __restrict__ Qh, u16* __restrict__ Ql,
               u16* __restrict__ Kh, u16* __restrict__ Kl,
               u16* __restrict__ Vh)
{
    const int z = blockIdx.z;
    const u16* __restrict__ Bh_ = (z==0)?Wqh:(z==1)?Wkh:Wvh;
    const u16* __restrict__ Bl_ = (z==0)?Wql:Wkl;   // unused when z==2
    const float* __restrict__ bias = (z==0)?bq:(z==1)?bk:bv;
    const bool spl = (z < 2);

    __shared__ __align__(16) u16 sAh[128*32];
    __shared__ __align__(16) u16 sAl[128*32];
    __shared__ __align__(16) u16 sBh[128*32];
    __shared__ __align__(16) u16 sBl[128*32];

    const int tid  = threadIdx.x;
    const int lane = tid & 63;
    const int ln   = lane & 15, quad = lane >> 4;
    const int w    = tid >> 6;
    const int wr   = (w & 1) * 64;
    const int wc   = (w >> 1) * 64;
    const int m0   = blockIdx.x * 128;
    const int n0   = blockIdx.y * 128;

    const int lr = lane >> 2;          // 0..15 row within 16-row chunk
    const int lc = (lane & 3) * 8;     // u16 col (0,8,16,24)

    f32x4 acc[4][4];
    const f32x4 z4 = {0.f,0.f,0.f,0.f};
#pragma unroll
    for (int s = 0; s < 4; ++s)
#pragma unroll
        for (int j = 0; j < 4; ++j) acc[s][j] = z4;

#pragma unroll 1
    for (int k0 = 0; k0 < D_MODEL; k0 += 32) {
        __syncthreads();   // previous tile fully consumed before DMA overwrite
#pragma unroll
        for (int cc = 0; cc < 2; ++cc) {
            const int c  = w*2 + cc;        // chunk 0..7 (16 rows each)
            const int gr = c*16 + lr;
            gload_lds16(&Xh [(size_t)(m0 + gr)*D_MODEL + k0 + lc], &sAh[c*512]);
            gload_lds16(&Bh_[(size_t)(n0 + gr)*D_MODEL + k0 + lc], &sBh[c*512]);
            if (spl) {
                gload_lds16(&Xl [(size_t)(m0 + gr)*D_MODEL + k0 + lc], &sAl[c*512]);
                gload_lds16(&Bl_[(size_t)(n0 + gr)*D_MODEL + k0 + lc], &sBl[c*512]);
            }
        }
        __syncthreads();   // drains vmcnt -> DMA data visible

        bf16x8 a_h[4], a_l[4];
#pragma unroll
        for (int s = 0; s < 4; ++s) {
            a_h[s] = *(const bf16x8*)&sAh[(wr + s*16 + ln)*32 + quad*8];
            if (spl) a_l[s] = *(const bf16x8*)&sAl[(wr + s*16 + ln)*32 + quad*8];
        }
#pragma unroll
        for (int j0 = 0; j0 < 4; ++j0) {
            bf16x8 b_h = *(const bf16x8*)&sBh[(wc + j0*16 + ln)*32 + quad*8];
            bf16x8 b_l;
            if (spl) b_l = *(const bf16x8*)&sBl[(wc + j0*16 + ln)*32 + quad*8];
#pragma unroll
            for (int s = 0; s < 4; ++s) {
                f32x4 t = __builtin_amdgcn_mfma_f32_16x16x32_bf16(a_h[s], b_h, acc[s][j0], 0, 0, 0);
                if (spl) {
                    t = __builtin_amdgcn_mfma_f32_16x16x32_bf16(a_l[s], b_h, t, 0, 0, 0);
                    t = __builtin_amdgcn_mfma_f32_16x16x32_bf16(a_h[s], b_l, t, 0, 0, 0);
                }
                acc[s][j0] = t;
            }
        }
    }

    // Q carries 1/8 * log2(e) so attn can use exp2 directly.
    const float scale = (z == 0) ? 0.125f * 1.4426950408889634f : 1.0f;
#pragma unroll
    for (int s = 0; s < 4; ++s) {
#pragma unroll
        for (int j0 = 0; j0 < 4; ++j0) {
            const int dfull = n0 + wc + j0*16 + ln;
            const int hh = dfull >> 6, dd = dfull & 63;
            const float bia = bias[dfull];
#pragma unroll
            for (int i = 0; i < 4; ++i) {
                int m  = m0 + wr + s*16 + quad*4 + i;
                int b_ = m >> 12, l = m & (SEQ-1);
                float v = (acc[s][j0][i] + bia) * scale;
                if (z < 2) {
                    u16 vh, vl; split_bf(v, vh, vl);
                    size_t idx = ((size_t)(b_*NUM_HEADS + hh)*SEQ + l)*D_K + dd;
                    if (z == 0) { Qh[idx] = vh; Ql[idx] = vl; }
                    else        { Kh[idx] = vh; Kl[idx] = vl; }
                } else {
                    int lp = (l & ~63) | ((l & 15) << 2) | ((l >> 4) & 3);
                    Vh[((size_t)(b_*NUM_HEADS + hh)*D_K + dd)*SEQ + lp] = f2bf(v);
                }
            }
        }
    }
}

// ---------------------------------------------------------------------------
// Output projection, MFMA plain bf16, global_load_lds staging.
// ---------------------------------------------------------------------------
__global__ __launch_bounds__(256)
void out_gemm(const u16* __restrict__ Ah, const u16* __restrict__ Bh_,
              const float* __restrict__ bias, float* __restrict__ C)
{
    __shared__ __align__(16) u16 sAh[128*32];
    __shared__ __align__(16) u16 sBh[128*32];

    const int tid  = threadIdx.x;
    const int lane = tid & 63;
    const int ln   = lane & 15, quad = lane >> 4;
    const int w    = tid >> 6;
    const int wr   = (w & 1) * 64;
    const int wc   = (w >> 1) * 64;
    const int m0   = blockIdx.x * 128;
    const int n0   = blockIdx.y * 128;
    const int lr = lane >> 2;
    const int lc = (lane & 3) * 8;

    f32x4 acc[4][4];
    const f32x4 z4 = {0.f,0.f,0.f,0.f};
#pragma unroll
    for (int s = 0; s < 4; ++s)
#pragma unroll
        for (int j = 0; j < 4; ++j) acc[s][j] = z4;

#pragma unroll 1
    for (int k0 = 0; k0 < D_MODEL; k0 += 32) {
        __syncthreads();
#pragma unroll
        for (int cc = 0; cc < 2; ++cc) {
            const int c  = w*2 + cc;
            const int gr = c*16 + lr;
            gload_lds16(&Ah [(size_t)(m0 + gr)*D_MODEL + k0 + lc], &sAh[c*512]);
            gload_lds16(&Bh_[(size_t)(n0 + gr)*D_MODEL + k0 + lc], &sBh[c*512]);
        }
        __syncthreads();

        bf16x8 a_h[4];
#pragma unroll
        for (int s = 0; s < 4; ++s)
            a_h[s] = *(const bf16x8*)&sAh[(wr + s*16 + ln)*32 + quad*8];
#pragma unroll
        for (int j0 = 0; j0 < 4; ++j0) {
            bf16x8 b_h = *(const bf16x8*)&sBh[(wc + j0*16 + ln)*32 + quad*8];
#pragma unroll
            for (int s = 0; s < 4; ++s)
                acc[s][j0] = __builtin_amdgcn_mfma_f32_16x16x32_bf16(a_h[s], b_h, acc[s][j0], 0, 0, 0);
        }
    }

#pragma unroll
    for (int s = 0; s < 4; ++s) {
#pragma unroll
        for (int j0 = 0; j0 < 4; ++j0) {
            const int dfull = n0 + wc + j0*16 + ln;
            const float bia = bias[dfull];
#pragma unroll
            for (int i = 0; i < 4; ++i) {
                int m = m0 + wr + s*16 + quad*4 + i;
                C[(size_t)m*D_MODEL + dfull] = acc[s][j0][i] + bia;
            }
        }
    }
}

// ---------------------------------------------------------------------------
// MFMA flash attention — LDS-staged K/V via global_load_lds DMA issued in
// EXACT fragment order: sub-chunk = 1 KiB where lane i's global 16 B is the
// fragment lane i reads back at (base + lane*16).  Staging costs zero VALU /
// zero explicit ds_writes; all K/V fragment reads are lane-contiguous
// (LDS-minimum b128 pattern, no padding needed).  24 sub-chunks per tile
// (K hi/lo x 4 j0 x 2 halves = 16, V x 8), 6 DMAs per wave.
// No-max softmax via exp2 (Q carries log2e/8); P truncated-bf16 via v_perm
// in a wave-private padded LDS region; l via ones-MFMA over the same
// truncated P (bias cancels in P/l).  LDS total 42 KB -> 3 blocks/CU.
// ---------------------------------------------------------------------------
#define LPP 72
#define SPOFF 12288   // u16 offset of P region (after 24 KB K/V)

__global__ __launch_bounds__(256)
void attn_mfma(const u16* __restrict__ Qh, const u16* __restrict__ Ql,
               const u16* __restrict__ Kh, const u16* __restrict__ Kl,
               const u16* __restrict__ Vh, u16* __restrict__ Obh)
{
    __shared__ __align__(16) u16 sm[SPOFF + 128*LPP];   // 43008 B

    const int tid  = threadIdx.x;
    const int w    = tid >> 6;
    const int lane = tid & 63;
    const int ln   = lane & 15;
    const int quad = lane >> 4;
    const int bh   = blockIdx.y;
    const int b_   = bh / NUM_HEADS;
    const int h    = bh % NUM_HEADS;
    const int q0   = blockIdx.x * 128;
    const int wq   = w * 32;

    const size_t bhL = (size_t)bh * SEQ;
    const u16* __restrict__ Kbh = Kh + bhL * D_K;                 // [key][dk]
    const u16* __restrict__ Kbl = Kl + bhL * D_K;
    const u16* __restrict__ Vb  = Vh + (size_t)bh * D_K * SEQ;    // [dk][key']

    // Q fragments (A-layout: m=ln, k=quad*8+j), hi & lo
    bf16x8 qh[2][2], ql[2][2];
#pragma unroll
    for (int s = 0; s < 2; ++s) {
        const size_t row = bhL + q0 + wq + s*16 + ln;
        const u16* qph = Qh + row * D_K;
        const u16* qpl = Ql + row * D_K;
        qh[s][0] = *(const bf16x8*)&qph[quad*8];
        qh[s][1] = *(const bf16x8*)&qph[32 + quad*8];
        ql[s][0] = *(const bf16x8*)&qpl[quad*8];
        ql[s][1] = *(const bf16x8*)&qpl[32 + quad*8];
    }

    const bf16x8 ones = {(short)0x3F80,(short)0x3F80,(short)0x3F80,(short)0x3F80,
                         (short)0x3F80,(short)0x3F80,(short)0x3F80,(short)0x3F80};
    const f32x4 z4 = {0.f,0.f,0.f,0.f};
    f32x4 lacc[2] = {z4, z4};
    f32x4 o[2][4];
#pragma unroll
    for (int s = 0; s < 2; ++s)
#pragma unroll
        for (int d0 = 0; d0 < 4; ++d0) o[s][d0] = z4;

    const int id0  = w * 6;           // this wave's 6 DMA sub-chunks
    const int lofs = lane * 8;        // this lane's 16 B frag within a chunk

#pragma unroll 1
    for (int kt = 0; kt < SEQ; kt += 64) {
        __syncthreads();   // previous tile fully consumed before DMA overwrite
#pragma unroll
        for (int t = 0; t < 6; ++t) {
            const int id = id0 + t;
            if (id < 16) {   // K: j0 (4) x hilo (2) x half (2)
                const int j0 = id >> 2, hilo = (id >> 1) & 1, hf = id & 1;
                const u16* src = (hilo ? Kbl : Kbh)
                               + (size_t)(kt + j0*16 + ln)*D_K + hf*32 + quad*8;
                gload_lds16(src, &sm[j0*2048 + hilo*1024 + hf*512]);
            } else {         // V: d0 (4) x half (2)
                const int vid = id - 16, d0 = vid >> 1, hf = vid & 1;
                const u16* src = Vb + (size_t)(d0*16 + ln)*SEQ + kt + hf*32 + quad*8;
                gload_lds16(src, &sm[8192 + d0*1024 + hf*512]);
            }
        }
        __syncthreads();   // drains vmcnt -> DMA data visible

        // ---- S = Q K^T : split-bf16, frags lane-contiguous in LDS ----
        f32x4 S[2][4];
#pragma unroll
        for (int j0 = 0; j0 < 4; ++j0) {
            bf16x8 kh0 = *(const bf16x8*)&sm[j0*2048        + lofs];
            bf16x8 kh1 = *(const bf16x8*)&sm[j0*2048 + 512  + lofs];
            bf16x8 kl0 = *(const bf16x8*)&sm[j0*2048 + 1024 + lofs];
            bf16x8 kl1 = *(const bf16x8*)&sm[j0*2048 + 1536 + lofs];
#pragma unroll
            for (int s = 0; s < 2; ++s) {
                f32x4 a = z4;
                a = __builtin_amdgcn_mfma_f32_16x16x32_bf16(qh[s][0], kh0, a, 0, 0, 0);
                a = __builtin_amdgcn_mfma_f32_16x16x32_bf16(ql[s][0], kh0, a, 0, 0, 0);
                a = __builtin_amdgcn_mfma_f32_16x16x32_bf16(qh[s][0], kl0, a, 0, 0, 0);
                a = __builtin_amdgcn_mfma_f32_16x16x32_bf16(qh[s][1], kh1, a, 0, 0, 0);
                a = __builtin_amdgcn_mfma_f32_16x16x32_bf16(ql[s][1], kh1, a, 0, 0, 0);
                a = __builtin_amdgcn_mfma_f32_16x16x32_bf16(qh[s][1], kl1, a, 0, 0, 0);
                S[s][j0] = a;
            }
        }

        // ---- P = exp2(S) (Q carries log2e); trunc-pack via v_perm ----
#pragma unroll
        for (int s = 0; s < 2; ++s) {
#pragma unroll
            for (int i = 0; i < 4; ++i) {
                u32 u0 = __float_as_uint(fast_exp2(S[s][0][i]));
                u32 u1 = __float_as_uint(fast_exp2(S[s][1][i]));
                u32 u2 = __float_as_uint(fast_exp2(S[s][2][i]));
                u32 u3 = __float_as_uint(fast_exp2(S[s][3][i]));
                uint2 pk;
                pk.x = __builtin_amdgcn_perm(u1, u0, 0x07060302u);  // {u0.hi, u1.hi}
                pk.y = __builtin_amdgcn_perm(u3, u2, 0x07060302u);  // {u2.hi, u3.hi}
                int prow = wq + s*16 + quad*4 + i;
                *(uint2*)&sm[SPOFF + prow*LPP + ln*4] = pk;
            }
        }

        // ---- O += P V ; l += P @ ones  (sP wave-private: no barrier) ----
        bf16x8 pa[2][2];
#pragma unroll
        for (int s = 0; s < 2; ++s) {
            const u16* pp = &sm[SPOFF + (wq + s*16 + ln)*LPP];
            pa[s][0] = *(const bf16x8*)&pp[quad*8];
            pa[s][1] = *(const bf16x8*)&pp[32 + quad*8];
        }
#pragma unroll
        for (int s = 0; s < 2; ++s) {
            lacc[s] = __builtin_amdgcn_mfma_f32_16x16x32_bf16(pa[s][0], ones, lacc[s], 0, 0, 0);
            lacc[s] = __builtin_amdgcn_mfma_f32_16x16x32_bf16(pa[s][1], ones, lacc[s], 0, 0, 0);
        }
#pragma unroll
        for (int d0 = 0; d0 < 4; ++d0) {
            bf16x8 vh0 = *(const bf16x8*)&sm[8192 + d0*1024       + lofs];
            bf16x8 vh1 = *(const bf16x8*)&sm[8192 + d0*1024 + 512 + lofs];
#pragma unroll
            for (int s = 0; s < 2; ++s) {
                f32x4 a = o[s][d0];
                a = __builtin_amdgcn_mfma_f32_16x16x32_bf16(pa[s][0], vh0, a, 0, 0, 0);
                a = __builtin_amdgcn_mfma_f32_16x16x32_bf16(pa[s][1], vh1, a, 0, 0, 0);
                o[s][d0] = a;
            }
        }
    }

    // ---- epilogue: l row-sums already in lacc (all lanes); store bf16 ----
#pragma unroll
    for (int s = 0; s < 2; ++s) {
        float inv[4];
#pragma unroll
        for (int i = 0; i < 4; ++i) inv[i] = 1.0f / lacc[s][i];
#pragma unroll
        for (int d0 = 0; d0 < 4; ++d0) {
#pragma unroll
            for (int i = 0; i < 4; ++i) {
                int q = q0 + wq + s*16 + quad*4 + i;
                Obh[((size_t)b_*SEQ + q)*D_MODEL + h*D_K + d0*16 + ln] =
                    f2bf(o[s][d0][i] * inv[i]);
            }
        }
    }
}

extern "C" void kernel_launch(void* const* d_in, const int* in_sizes, int n_in,
                              void* d_out, int out_size, void* d_ws, size_t ws_size,
                              hipStream_t stream)
{
    const float* x  = (const float*)d_in[0];
    const float* Wq = (const float*)d_in[1];
    const float* bq = (const float*)d_in[2];
    const float* Wk = (const float*)d_in[3];
    const float* bk = (const float*)d_in[4];
    const float* Wv = (const float*)d_in[5];
    const float* bv = (const float*)d_in[6];
    const float* Wo = (const float*)d_in[7];
    const float* bo = (const float*)d_in[8];
    float* out = (float*)d_out;

    const size_t nX = (size_t)MROWS * D_MODEL;    // 6291456
    const size_t nW = (size_t)D_MODEL * D_MODEL;  // 589824

    u16* Xh  = (u16*)d_ws;
    u16* Xl  = Xh  + nX;
    u16* Wqh = Xl  + nX;
    u16* Wql = Wqh + nW;
    u16* Wkh = Wql + nW;
    u16* Wkl = Wkh + nW;
    u16* Wvh = Wkl + nW;
    u16* Woh = Wvh + nW;
    u16* Qh  = Woh + nW;
    u16* Ql  = Qh  + nX;
    u16* Kh  = Ql  + nX;
    u16* Kl  = Kh  + nX;
    u16* Vh  = Kl  + nX;
    u16* Obh = Xh;                 // alias: Xh/Xl dead after proj_gemm

    dim3 blk(256);
    convert_x<<<dim3(nX/(256*8)), blk, 0, stream>>>(x, Xh, Xl);
    convert_w<<<dim3(nW/(256*8), 4), blk, 0, stream>>>(Wq, Wk, Wv, Wo,
                                                       Wqh, Wql, Wkh, Wkl, Wvh, Woh);
    proj_gemm<<<dim3(MROWS/128, D_MODEL/128, 3), blk, 0, stream>>>(
        Xh, Xl, Wqh, Wql, Wkh, Wkl, Wvh, bq, bk, bv, Qh, Ql, Kh, Kl, Vh);
    attn_mfma<<<dim3(SEQ/128, BH_), blk, 0, stream>>>(Qh, Ql, Kh, Kl, Vh, Obh);
    out_gemm<<<dim3(MROWS/128, D_MODEL/128), blk, 0, stream>>>(Obh, Woh, bo, out);
}

// Round 7
// 388.348 us; speedup vs baseline: 2.2295x; 1.1935x over previous
//
#include <hip/hip_runtime.h>
#include <math.h>

#define D_MODEL 768
#define NUM_HEADS 12
#define D_K 64
#define SEQ 4096
#define BATCH 2
#define BH_ (BATCH*NUM_HEADS)
#define MROWS (BATCH*SEQ)     // 8192

typedef __attribute__((ext_vector_type(8))) short bf16x8;
typedef __attribute__((ext_vector_type(4))) float f32x4;
typedef unsigned short u16;
typedef unsigned int u32;

__device__ __forceinline__ u16 f2bf(float f) {
    union { float f; u32 u; } v; v.f = f;
    u32 r = v.u + 0x7fffu + ((v.u >> 16) & 1u);   // RNE
    return (u16)(r >> 16);
}
__device__ __forceinline__ float bf2f(u16 h) {
    union { u32 u; float f; } v; v.u = (u32)h << 16; return v.f;
}
__device__ __forceinline__ void split_bf(float v, u16& h, u16& l) {
    h = f2bf(v); l = f2bf(v - bf2f(h));
}
__device__ __forceinline__ float fast_exp2(float x) {
#if __has_builtin(__builtin_amdgcn_exp2f)
    return __builtin_amdgcn_exp2f(x);
#else
    return exp2f(x);
#endif
}
// async global->LDS DMA: LDS dest = uniform base + lane*16
__device__ __forceinline__ void gload_lds16(const u16* g, u16* l) {
    __builtin_amdgcn_global_load_lds(
        (const __attribute__((address_space(1))) void*)g,
        (__attribute__((address_space(3))) void*)l, 16, 0, 0);
}
__device__ __forceinline__ f32x4 mfma16(bf16x8 a, bf16x8 b, f32x4 c) {
    return __builtin_amdgcn_mfma_f32_16x16x32_bf16(a, b, c, 0, 0, 0);
}

// ---------------------------------------------------------------------------
// convert x -> Xh, Xl (split bf16).  8 elements / thread.
// ---------------------------------------------------------------------------
__global__ __launch_bounds__(256)
void convert_x(const float* __restrict__ x, u16* __restrict__ Xh, u16* __restrict__ Xl)
{
    int i = (blockIdx.x * 256 + threadIdx.x) * 8;
    float4 a = *(const float4*)&x[i];
    float4 b = *(const float4*)&x[i + 4];
    float vs[8] = {a.x, a.y, a.z, a.w, b.x, b.y, b.z, b.w};
    u16 hs[8], ls[8];
#pragma unroll
    for (int j = 0; j < 8; ++j) split_bf(vs[j], hs[j], ls[j]);
    uint4 H, L;
    H.x = (u32)hs[0] | ((u32)hs[1] << 16); H.y = (u32)hs[2] | ((u32)hs[3] << 16);
    H.z = (u32)hs[4] | ((u32)hs[5] << 16); H.w = (u32)hs[6] | ((u32)hs[7] << 16);
    L.x = (u32)ls[0] | ((u32)ls[1] << 16); L.y = (u32)ls[2] | ((u32)ls[3] << 16);
    L.z = (u32)ls[4] | ((u32)ls[5] << 16); L.w = (u32)ls[6] | ((u32)ls[7] << 16);
    *(uint4*)&Xh[i] = H;
    *(uint4*)&Xl[i] = L;
}

// ---------------------------------------------------------------------------
// convert weights.  z=0: Wq->h+l  z=1: Wk->h+l  z=2: Wv->h  z=3: Wo->h
// ---------------------------------------------------------------------------
__global__ __launch_bounds__(256)
void convert_w(const float* __restrict__ Wq, const float* __restrict__ Wk,
               const float* __restrict__ Wv, const float* __restrict__ Wo,
               u16* __restrict__ Wqh, u16* __restrict__ Wql,
               u16* __restrict__ Wkh, u16* __restrict__ Wkl,
               u16* __restrict__ Wvh, u16* __restrict__ Woh)
{
    const int z = blockIdx.y;
    const float* __restrict__ src = (z==0)?Wq:(z==1)?Wk:(z==2)?Wv:Wo;
    u16* __restrict__ dh = (z==0)?Wqh:(z==1)?Wkh:(z==2)?Wvh:Woh;
    u16* __restrict__ dl = (z==0)?Wql:(z==1)?Wkl:nullptr;

    int i = (blockIdx.x * 256 + threadIdx.x) * 8;
    float4 a = *(const float4*)&src[i];
    float4 b = *(const float4*)&src[i + 4];
    float vs[8] = {a.x, a.y, a.z, a.w, b.x, b.y, b.z, b.w};
    u16 hs[8], ls[8];
#pragma unroll
    for (int j = 0; j < 8; ++j) split_bf(vs[j], hs[j], ls[j]);
    uint4 H;
    H.x = (u32)hs[0] | ((u32)hs[1] << 16); H.y = (u32)hs[2] | ((u32)hs[3] << 16);
    H.z = (u32)hs[4] | ((u32)hs[5] << 16); H.w = (u32)hs[6] | ((u32)hs[7] << 16);
    *(uint4*)&dh[i] = H;
    if (dl) {
        uint4 L;
        L.x = (u32)ls[0] | ((u32)ls[1] << 16); L.y = (u32)ls[2] | ((u32)ls[3] << 16);
        L.z = (u32)ls[4] | ((u32)ls[5] << 16); L.w = (u32)ls[6] | ((u32)ls[7] << 16);
        *(uint4*)&dl[i] = L;
    }
}

// ---------------------------------------------------------------------------
// QKV projection, MFMA.  128x128 tile, BK=32, 4 waves (2x2 of 64x64).
// Staging via global_load_lds (m97 pattern, unpadded 32-elem rows).
// ---------------------------------------------------------------------------
__global__ __launch_bounds__(256)
void proj_gemm(const u16* __restrict__ Xh, const u16* __restrict__ Xl,
               const u16* __restrict__ Wqh, const u16* __restrict__ Wql,
               const u16* __restrict__ Wkh, const u16* __restrict__ Wkl,
               const u16* __restrict__ Wvh,
               const float* __restrict__ bq, const float* __restrict__ bk,
               const float* __restrict__ bv,
               u16* __restrict__ Qh, u16* __restrict__ Ql,
               u16* __restrict__ Kh, u16* __restrict__ Kl,
               u16* __restrict__ Vh)
{
    const int z = blockIdx.z;
    const u16* __restrict__ Bh_ = (z==0)?Wqh:(z==1)?Wkh:Wvh;
    const u16* __restrict__ Bl_ = (z==0)?Wql:Wkl;   // unused when z==2
    const float* __restrict__ bias = (z==0)?bq:(z==1)?bk:bv;
    const bool spl = (z < 2);

    __shared__ __align__(16) u16 sAh[128*32];
    __shared__ __align__(16) u16 sAl[128*32];
    __shared__ __align__(16) u16 sBh[128*32];
    __shared__ __align__(16) u16 sBl[128*32];

    const int tid  = threadIdx.x;
    const int lane = tid & 63;
    const int ln   = lane & 15, quad = lane >> 4;
    const int w    = tid >> 6;
    const int wr   = (w & 1) * 64;
    const int wc   = (w >> 1) * 64;
    const int m0   = blockIdx.x * 128;
    const int n0   = blockIdx.y * 128;

    const int lr = lane >> 2;          // 0..15 row within 16-row chunk
    const int lc = (lane & 3) * 8;     // u16 col (0,8,16,24)

    f32x4 acc[4][4];
    const f32x4 z4 = {0.f,0.f,0.f,0.f};
#pragma unroll
    for (int s = 0; s < 4; ++s)
#pragma unroll
        for (int j = 0; j < 4; ++j) acc[s][j] = z4;

#pragma unroll 1
    for (int k0 = 0; k0 < D_MODEL; k0 += 32) {
        __syncthreads();   // previous tile fully consumed before DMA overwrite
#pragma unroll
        for (int cc = 0; cc < 2; ++cc) {
            const int c  = w*2 + cc;        // chunk 0..7 (16 rows each)
            const int gr = c*16 + lr;
            gload_lds16(&Xh [(size_t)(m0 + gr)*D_MODEL + k0 + lc], &sAh[c*512]);
            gload_lds16(&Bh_[(size_t)(n0 + gr)*D_MODEL + k0 + lc], &sBh[c*512]);
            if (spl) {
                gload_lds16(&Xl [(size_t)(m0 + gr)*D_MODEL + k0 + lc], &sAl[c*512]);
                gload_lds16(&Bl_[(size_t)(n0 + gr)*D_MODEL + k0 + lc], &sBl[c*512]);
            }
        }
        __syncthreads();   // drains vmcnt -> DMA data visible

        bf16x8 a_h[4], a_l[4];
#pragma unroll
        for (int s = 0; s < 4; ++s) {
            a_h[s] = *(const bf16x8*)&sAh[(wr + s*16 + ln)*32 + quad*8];
            if (spl) a_l[s] = *(const bf16x8*)&sAl[(wr + s*16 + ln)*32 + quad*8];
        }
#pragma unroll
        for (int j0 = 0; j0 < 4; ++j0) {
            bf16x8 b_h = *(const bf16x8*)&sBh[(wc + j0*16 + ln)*32 + quad*8];
            bf16x8 b_l;
            if (spl) b_l = *(const bf16x8*)&sBl[(wc + j0*16 + ln)*32 + quad*8];
#pragma unroll
            for (int s = 0; s < 4; ++s) {
                f32x4 t = mfma16(a_h[s], b_h, acc[s][j0]);
                if (spl) {
                    t = mfma16(a_l[s], b_h, t);
                    t = mfma16(a_h[s], b_l, t);
                }
                acc[s][j0] = t;
            }
        }
    }

    // Q carries 1/8 * log2(e) so attn can use exp2 directly.
    const float scale = (z == 0) ? 0.125f * 1.4426950408889634f : 1.0f;
#pragma unroll
    for (int s = 0; s < 4; ++s) {
#pragma unroll
        for (int j0 = 0; j0 < 4; ++j0) {
            const int dfull = n0 + wc + j0*16 + ln;
            const int hh = dfull >> 6, dd = dfull & 63;
            const float bia = bias[dfull];
#pragma unroll
            for (int i = 0; i < 4; ++i) {
                int m  = m0 + wr + s*16 + quad*4 + i;
                int b_ = m >> 12, l = m & (SEQ-1);
                float v = (acc[s][j0][i] + bia) * scale;
                if (z < 2) {
                    u16 vh, vl; split_bf(v, vh, vl);
                    size_t idx = ((size_t)(b_*NUM_HEADS + hh)*SEQ + l)*D_K + dd;
                    if (z == 0) { Qh[idx] = vh; Ql[idx] = vl; }
                    else        { Kh[idx] = vh; Kl[idx] = vl; }
                } else {
                    int lp = (l & ~63) | ((l & 15) << 2) | ((l >> 4) & 3);
                    Vh[((size_t)(b_*NUM_HEADS + hh)*D_K + dd)*SEQ + lp] = f2bf(v);
                }
            }
        }
    }
}

// ---------------------------------------------------------------------------
// Output projection, MFMA plain bf16, global_load_lds staging.
// ---------------------------------------------------------------------------
__global__ __launch_bounds__(256)
void out_gemm(const u16* __restrict__ Ah, const u16* __restrict__ Bh_,
              const float* __restrict__ bias, float* __restrict__ C)
{
    __shared__ __align__(16) u16 sAh[128*32];
    __shared__ __align__(16) u16 sBh[128*32];

    const int tid  = threadIdx.x;
    const int lane = tid & 63;
    const int ln   = lane & 15, quad = lane >> 4;
    const int w    = tid >> 6;
    const int wr   = (w & 1) * 64;
    const int wc   = (w >> 1) * 64;
    const int m0   = blockIdx.x * 128;
    const int n0   = blockIdx.y * 128;
    const int lr = lane >> 2;
    const int lc = (lane & 3) * 8;

    f32x4 acc[4][4];
    const f32x4 z4 = {0.f,0.f,0.f,0.f};
#pragma unroll
    for (int s = 0; s < 4; ++s)
#pragma unroll
        for (int j = 0; j < 4; ++j) acc[s][j] = z4;

#pragma unroll 1
    for (int k0 = 0; k0 < D_MODEL; k0 += 32) {
        __syncthreads();
#pragma unroll
        for (int cc = 0; cc < 2; ++cc) {
            const int c  = w*2 + cc;
            const int gr = c*16 + lr;
            gload_lds16(&Ah [(size_t)(m0 + gr)*D_MODEL + k0 + lc], &sAh[c*512]);
            gload_lds16(&Bh_[(size_t)(n0 + gr)*D_MODEL + k0 + lc], &sBh[c*512]);
        }
        __syncthreads();

        bf16x8 a_h[4];
#pragma unroll
        for (int s = 0; s < 4; ++s)
            a_h[s] = *(const bf16x8*)&sAh[(wr + s*16 + ln)*32 + quad*8];
#pragma unroll
        for (int j0 = 0; j0 < 4; ++j0) {
            bf16x8 b_h = *(const bf16x8*)&sBh[(wc + j0*16 + ln)*32 + quad*8];
#pragma unroll
            for (int s = 0; s < 4; ++s)
                acc[s][j0] = mfma16(a_h[s], b_h, acc[s][j0]);
        }
    }

#pragma unroll
    for (int s = 0; s < 4; ++s) {
#pragma unroll
        for (int j0 = 0; j0 < 4; ++j0) {
            const int dfull = n0 + wc + j0*16 + ln;
            const float bia = bias[dfull];
#pragma unroll
            for (int i = 0; i < 4; ++i) {
                int m = m0 + wr + s*16 + quad*4 + i;
                C[(size_t)m*D_MODEL + dfull] = acc[s][j0][i] + bia;
            }
        }
    }
}

// ---------------------------------------------------------------------------
// MFMA flash attention — prefetch-pipelined, ONE __syncthreads per tile.
// V double-buffered (sV0/sV1): prefetch for tile k+1 issued right after the
// top barrier of tile k, drained by the NEXT tile's barrier (the drain IS the
// producer-consumer wait; ~500-cyc in-flight window).
// K single-buffered: K frags consumed into registers during QK; a raw
// "lgkmcnt(0); s_barrier" (no vmcnt drain) then releases sK for the K-prefetch
// while exp/P/PV run from registers.
// DMA chunks are in exact fragment order (lane i's 16 B = its frag).
// Separate __shared__ objects keep LDS-DMA waitcnt tracking per-object.
// LDS 50 KB -> 3 blocks/CU (768 blocks = exactly full residency).
// ---------------------------------------------------------------------------
#define LPP 72

__global__ __launch_bounds__(256, 3)
void attn_mfma(const u16* __restrict__ Qh, const u16* __restrict__ Ql,
               const u16* __restrict__ Kh, const u16* __restrict__ Kl,
               const u16* __restrict__ Vh, u16* __restrict__ Obh)
{
    __shared__ __align__(16) u16 sK [8192];   // j0*2048 + hilo*1024 + half*512
    __shared__ __align__(16) u16 sV0[4096];   // d0*1024 + half*512
    __shared__ __align__(16) u16 sV1[4096];
    __shared__ __align__(16) u16 sP [128*LPP];

    const int tid  = threadIdx.x;
    const int w    = tid >> 6;
    const int lane = tid & 63;
    const int ln   = lane & 15;
    const int quad = lane >> 4;
    const int bh   = blockIdx.y;
    const int b_   = bh / NUM_HEADS;
    const int h    = bh % NUM_HEADS;
    const int q0   = blockIdx.x * 128;
    const int wq   = w * 32;
    const int lofs = lane * 8;        // this lane's 16 B frag within a 1 KiB chunk

    const size_t bhL = (size_t)bh * SEQ;
    const u16* __restrict__ Kbh = Kh + bhL * D_K;                 // [key][dk]
    const u16* __restrict__ Kbl = Kl + bhL * D_K;
    const u16* __restrict__ Vb  = Vh + (size_t)bh * D_K * SEQ;    // [dk][key']

    // Q fragments (A-layout: m=ln, k=quad*8+j), hi & lo
    bf16x8 qh[2][2], ql[2][2];
#pragma unroll
    for (int s = 0; s < 2; ++s) {
        const size_t row = bhL + q0 + wq + s*16 + ln;
        const u16* qph = Qh + row * D_K;
        const u16* qpl = Ql + row * D_K;
        qh[s][0] = *(const bf16x8*)&qph[quad*8];
        qh[s][1] = *(const bf16x8*)&qph[32 + quad*8];
        ql[s][0] = *(const bf16x8*)&qpl[quad*8];
        ql[s][1] = *(const bf16x8*)&qpl[32 + quad*8];
    }

    const bf16x8 ones = {(short)0x3F80,(short)0x3F80,(short)0x3F80,(short)0x3F80,
                         (short)0x3F80,(short)0x3F80,(short)0x3F80,(short)0x3F80};
    const f32x4 z4 = {0.f,0.f,0.f,0.f};
    f32x4 lacc[2] = {z4, z4};
    f32x4 o[2][4];
#pragma unroll
    for (int s = 0; s < 2; ++s)
#pragma unroll
        for (int d0 = 0; d0 < 4; ++d0) o[s][d0] = z4;

    // ---- prologue: DMA tile 0 (wave w stages K j0=w and V d0=w) ----
    gload_lds16(Vb + (size_t)(w*16 + ln)*SEQ + quad*8,      &sV0[w*1024]);
    gload_lds16(Vb + (size_t)(w*16 + ln)*SEQ + 32 + quad*8, &sV0[w*1024 + 512]);
#pragma unroll
    for (int t = 0; t < 4; ++t) {
        const u16* ksrc = ((t >> 1) ? Kbl : Kbh)
                        + (size_t)(w*16 + ln)*D_K + (t & 1)*32 + quad*8;
        gload_lds16(ksrc, &sK[w*2048 + (t>>1)*1024 + (t&1)*512]);
    }

#define ATTN_BODY(SVC, SVN, KTN)                                               \
    {                                                                          \
        __syncthreads();  /* drains vmcnt: this tile's K+V DMAs visible */     \
        /* V prefetch for next tile (other buffer: released by the barrier) */ \
        gload_lds16(Vb + (size_t)(w*16 + ln)*SEQ + (KTN) + quad*8,             \
                    &SVN[w*1024]);                                             \
        gload_lds16(Vb + (size_t)(w*16 + ln)*SEQ + (KTN) + 32 + quad*8,        \
                    &SVN[w*1024 + 512]);                                       \
        /* S = Q K^T : split-bf16, K frags -> registers */                     \
        f32x4 S[2][4];                                                         \
        _Pragma("unroll")                                                      \
        for (int j0 = 0; j0 < 4; ++j0) {                                       \
            bf16x8 kh0 = *(const bf16x8*)&sK[j0*2048        + lofs];           \
            bf16x8 kh1 = *(const bf16x8*)&sK[j0*2048 + 512  + lofs];           \
            bf16x8 kl0 = *(const bf16x8*)&sK[j0*2048 + 1024 + lofs];           \
            bf16x8 kl1 = *(const bf16x8*)&sK[j0*2048 + 1536 + lofs];           \
            _Pragma("unroll")                                                  \
            for (int s = 0; s < 2; ++s) {                                      \
                f32x4 a = z4;                                                  \
                a = mfma16(qh[s][0], kh0, a);                                  \
                a = mfma16(ql[s][0], kh0, a);                                  \
                a = mfma16(qh[s][0], kl0, a);                                  \
                a = mfma16(qh[s][1], kh1, a);                                  \
                a = mfma16(ql[s][1], kh1, a);                                  \
                a = mfma16(qh[s][1], kl1, a);                                  \
                S[s][j0] = a;                                                  \
            }                                                                  \
        }                                                                      \
        /* all waves' K reads retired -> release sK, prefetch next K tile */   \
        asm volatile("s_waitcnt lgkmcnt(0)\n\ts_barrier" ::: "memory");        \
        _Pragma("unroll")                                                      \
        for (int t = 0; t < 4; ++t) {                                          \
            const u16* ksrc = ((t >> 1) ? Kbl : Kbh)                           \
                            + (size_t)((KTN) + w*16 + ln)*D_K                  \
                            + (t & 1)*32 + quad*8;                             \
            gload_lds16(ksrc, &sK[w*2048 + (t>>1)*1024 + (t&1)*512]);          \
        }                                                                      \
        /* P = exp2(S); trunc-pack via v_perm into wave-private sP */          \
        _Pragma("unroll")                                                      \
        for (int s = 0; s < 2; ++s) {                                          \
            _Pragma("unroll")                                                  \
            for (int i = 0; i < 4; ++i) {                                      \
                u32 u0 = __float_as_uint(fast_exp2(S[s][0][i]));               \
                u32 u1 = __float_as_uint(fast_exp2(S[s][1][i]));               \
                u32 u2 = __float_as_uint(fast_exp2(S[s][2][i]));               \
                u32 u3 = __float_as_uint(fast_exp2(S[s][3][i]));               \
                uint2 pk;                                                      \
                pk.x = __builtin_amdgcn_perm(u1, u0, 0x07060302u);             \
                pk.y = __builtin_amdgcn_perm(u3, u2, 0x07060302u);             \
                int prow = wq + s*16 + quad*4 + i;                             \
                *(uint2*)&sP[prow*LPP + ln*4] = pk;                            \
            }                                                                  \
        }                                                                      \
        /* O += P V ; l += P @ ones  (sP wave-private: no barrier) */          \
        bf16x8 pa[2][2];                                                       \
        _Pragma("unroll")                                                      \
        for (int s = 0; s < 2; ++s) {                                          \
            const u16* pp = &sP[(wq + s*16 + ln)*LPP];                         \
            pa[s][0] = *(const bf16x8*)&pp[quad*8];                            \
            pa[s][1] = *(const bf16x8*)&pp[32 + quad*8];                       \
        }                                                                      \
        _Pragma("unroll")                                                      \
        for (int s = 0; s < 2; ++s) {                                          \
            lacc[s] = mfma16(pa[s][0], ones, lacc[s]);                         \
            lacc[s] = mfma16(pa[s][1], ones, lacc[s]);                         \
        }                                                                      \
        _Pragma("unroll")                                                      \
        for (int d0 = 0; d0 < 4; ++d0) {                                       \
            bf16x8 vh0 = *(const bf16x8*)&SVC[d0*1024       + lofs];           \
            bf16x8 vh1 = *(const bf16x8*)&SVC[d0*1024 + 512 + lofs];           \
            _Pragma("unroll")                                                  \
            for (int s = 0; s < 2; ++s) {                                      \
                f32x4 a = o[s][d0];                                            \
                a = mfma16(pa[s][0], vh0, a);                                  \
                a = mfma16(pa[s][1], vh1, a);                                  \
                o[s][d0] = a;                                                  \
            }                                                                  \
        }                                                                      \
    }

#pragma unroll 1
    for (int kt = 0; kt < SEQ; kt += 128) {
        const int kn1 = kt + 64;
        const int kn2 = (kt + 128 == SEQ) ? 0 : kt + 128;   // wrap: harmless
        ATTN_BODY(sV0, sV1, kn1)
        ATTN_BODY(sV1, sV0, kn2)
    }
#undef ATTN_BODY

    // ---- epilogue: l row-sums already in lacc (all lanes); store bf16 ----
#pragma unroll
    for (int s = 0; s < 2; ++s) {
        float inv[4];
#pragma unroll
        for (int i = 0; i < 4; ++i) inv[i] = 1.0f / lacc[s][i];
#pragma unroll
        for (int d0 = 0; d0 < 4; ++d0) {
#pragma unroll
            for (int i = 0; i < 4; ++i) {
                int q = q0 + wq + s*16 + quad*4 + i;
                Obh[((size_t)b_*SEQ + q)*D_MODEL + h*D_K + d0*16 + ln] =
                    f2bf(o[s][d0][i] * inv[i]);
            }
        }
    }
}

extern "C" void kernel_launch(void* const* d_in, const int* in_sizes, int n_in,
                              void* d_out, int out_size, void* d_ws, size_t ws_size,
                              hipStream_t stream)
{
    const float* x  = (const float*)d_in[0];
    const float* Wq = (const float*)d_in[1];
    const float* bq = (const float*)d_in[2];
    const float* Wk = (const float*)d_in[3];
    const float* bk = (const float*)d_in[4];
    const float* Wv = (const float*)d_in[5];
    const float* bv = (const float*)d_in[6];
    const float* Wo = (const float*)d_in[7];
    const float* bo = (const float*)d_in[8];
    float* out = (float*)d_out;

    const size_t nX = (size_t)MROWS * D_MODEL;    // 6291456
    const size_t nW = (size_t)D_MODEL * D_MODEL;  // 589824

    u16* Xh  = (u16*)d_ws;
    u16* Xl  = Xh  + nX;
    u16* Wqh = Xl  + nX;
    u16* Wql = Wqh + nW;
    u16* Wkh = Wql + nW;
    u16* Wkl = Wkh + nW;
    u16* Wvh = Wkl + nW;
    u16* Woh = Wvh + nW;
    u16* Qh  = Woh + nW;
    u16* Ql  = Qh  + nX;
    u16* Kh  = Ql  + nX;
    u16* Kl  = Kh  + nX;
    u16* Vh  = Kl  + nX;
    u16* Obh = Xh;                 // alias: Xh/Xl dead after proj_gemm

    dim3 blk(256);
    convert_x<<<dim3(nX/(256*8)), blk, 0, stream>>>(x, Xh, Xl);
    convert_w<<<dim3(nW/(256*8), 4), blk, 0, stream>>>(Wq, Wk, Wv, Wo,
                                                       Wqh, Wql, Wkh, Wkl, Wvh, Woh);
    proj_gemm<<<dim3(MROWS/128, D_MODEL/128, 3), blk, 0, stream>>>(
        Xh, Xl, Wqh, Wql, Wkh, Wkl, Wvh, bq, bk, bv, Qh, Ql, Kh, Kl, Vh);
    attn_mfma<<<dim3(SEQ/128, BH_), blk, 0, stream>>>(Qh, Ql, Kh, Kl, Vh, Obh);
    out_gemm<<<dim3(MROWS/128, D_MODEL/128), blk, 0, stream>>>(Obh, Woh, bo, out);
}